// Round 2
// baseline (427.450 us; speedup 1.0000x reference)
//
#include <hip/hip_runtime.h>

#define N_ENT 100000
#define DIM 512
#define RANK 256
#define HROWS 256
#define MAXOBS 32

typedef __attribute__((ext_vector_type(8))) short short8_t;
typedef __attribute__((ext_vector_type(4))) float f32x4;
typedef __attribute__((ext_vector_type(4))) unsigned int u32x4;

__device__ __forceinline__ unsigned short f2bf(float f) {
  unsigned int x = __float_as_uint(f);
  x = x + 0x7fffu + ((x >> 16) & 1u);
  return (unsigned short)(x >> 16);
}

// ---- mask format handling (bool storage dtype is harness-dependent) ----
__device__ __forceinline__ int mask_mode(const int* flags) {
  int nz0 = flags[0], nz1 = flags[1], nz2 = flags[2], nz3 = flags[3];
  if (nz1 || (nz0 && (nz2 | nz3))) return 0;  // uint8
  if (nz0) return 1;                          // int32
  if (nz2 | nz3) return 2;                    // float32
  return 0;
}

__device__ __forceinline__ int mask_at(const void* mask, int idx, int mode) {
  if (mode == 0) return ((const unsigned char*)mask)[idx] != 0;
  if (mode == 1) return ((const int*)mask)[idx] != 0;
  return ((const float*)mask)[idx] != 0.0f;
}

__global__ void detect_mask_kernel(const unsigned char* __restrict__ mb, int* flags) {
  int t = threadIdx.x;
  int nz[4] = {0, 0, 0, 0};
  for (int j = 0; j < 32; ++j) {
    int idx = t * 32 + j;
    if (mb[idx]) nz[idx & 3] = 1;
  }
  for (int r = 0; r < 4; ++r)
    if (nz[r]) atomicOr(&flags[r], 1);
}

// ---- head extraction ----
__global__ void find_heads_kernel(const float* __restrict__ vec, int* counter, int* tmp) {
  int i = blockIdx.x * blockDim.x + threadIdx.x;
  if (i < N_ENT && vec[i] != 0.0f) {
    int p = atomicAdd(counter, 1);
    if (p < HROWS) tmp[p] = i;
  }
}

__global__ void sort_heads_kernel(const int* __restrict__ counter, const int* __restrict__ tmp,
                                  int* __restrict__ heads) {
  __shared__ int v[HROWS];
  int t = threadIdx.x;
  int cnt = *counter;
  if (cnt > HROWS) cnt = HROWS;
  v[t] = (t < cnt) ? tmp[t] : 0x7fffffff;
  __syncthreads();
  for (int k = 2; k <= HROWS; k <<= 1) {
    for (int j = k >> 1; j > 0; j >>= 1) {
      int ixj = t ^ j;
      if (ixj > t) {
        int a = v[t], b = v[ixj];
        bool up = ((t & k) == 0);
        if ((a > b) == up) { v[t] = b; v[ixj] = a; }
      }
      __syncthreads();
    }
  }
  heads[t] = (v[t] == 0x7fffffff) ? 0 : v[t];
}

// ---- query build ----
__global__ void build_q_kernel(const float* __restrict__ ent, const float* __restrict__ rel,
                               const int* __restrict__ heads, const int* __restrict__ rel_id,
                               unsigned short* __restrict__ q) {
  int b = blockIdx.x, k = threadIdx.x;
  int h = heads[b];
  const float* r = rel + (size_t)(*rel_id) * (2 * RANK);
  float re_h = ent[(size_t)h * DIM + k];
  float im_h = ent[(size_t)h * DIM + RANK + k];
  float re_r = r[k], im_r = r[RANK + k];
  q[(size_t)b * DIM + k]        = f2bf(re_h * re_r - im_h * im_r);
  q[(size_t)b * DIM + RANK + k] = f2bf(re_h * im_r + im_h * re_r);
}

// ---- GEMM: p_un = exp(q(256x512) @ ent^T) ; also per-row sums ----
// grid (782, 2), 256 thr (4 waves, 2x2). Block tile 128 rows x 128 cols, BK=64.
// A = q bf16 via global_load_lds (pre-swizzled src); B = ent f32 reg-staged ->
// cvt_pk bf16 -> swizzled ds_write. LDS 64 KB double-buffered, 1 barrier/step.
__global__ __launch_bounds__(256) void gemm_scores_kernel(
    const float* __restrict__ ent, const unsigned short* __restrict__ q,
    float* __restrict__ out, float* __restrict__ rowsum) {
  __shared__ __align__(16) unsigned short As[2][128 * 64];
  __shared__ __align__(16) unsigned short Bs[2][128 * 64];

  const int t = threadIdx.x;
  const int lane = t & 63;
  const int w = t >> 6;
  const int wm = w >> 1, wn = w & 1;
  const int lrow = lane & 15;
  const int lk8 = (lane >> 4) * 8;

  // XCD-bijective block swizzle (m204)
  int bx = blockIdx.x;
  {
    const int nwg = gridDim.x;
    const int qq = nwg >> 3, rr = nwg & 7;
    const int xcd = bx & 7, off = bx >> 3;
    bx = (xcd < rr ? xcd * (qq + 1) : rr * (qq + 1) + (xcd - rr) * qq) + off;
  }
  const int e0 = bx * 128;
  const int my = blockIdx.y * 128;

  // staging geometry: tiles are 128 rows x 64 k = 1024 chunks of 16B; 4/thread.
  const unsigned short* aptr[4];
  const float* bptr[4];
  int bdst[4];
#pragma unroll
  for (int i = 0; i < 4; ++i) {
    const int n = i * 256 + t;
    const int row = n >> 3, slot = n & 7;
    const int sw = (row & 7) << 4;
    // A: linear LDS dest (gl_lds), so PRE-SWIZZLE the global source (rule #21)
    aptr[i] = q + (size_t)(my + row) * DIM + ((((slot << 4) ^ sw)) >> 1);
    // B: reg-staged, so write-side swizzle; source linear
    int gr = e0 + row; if (gr > N_ENT - 1) gr = N_ENT - 1;
    bptr[i] = ent + (size_t)gr * DIM + slot * 8;
    bdst[i] = row * 128 + ((slot << 4) ^ sw);
  }

  float4 br[4][2];
  auto bload = [&](int s) {
#pragma unroll
    for (int i = 0; i < 4; ++i) {
      br[i][0] = *reinterpret_cast<const float4*>(bptr[i] + s * 64);
      br[i][1] = *reinterpret_cast<const float4*>(bptr[i] + s * 64 + 4);
    }
  };
  auto astage = [&](int buf, int s) {
#pragma unroll
    for (int i = 0; i < 4; ++i) {
      __builtin_amdgcn_global_load_lds(
          (const __attribute__((address_space(1))) void*)(aptr[i] + s * 64),
          (__attribute__((address_space(3))) void*)((char*)&As[0][0] + buf * 16384 +
                                                    (i * 256 + (t & 192)) * 16),
          16, 0, 0);
    }
  };
  auto bwrite = [&](int buf) {
#pragma unroll
    for (int i = 0; i < 4; ++i) {
      unsigned int r0, r1, r2, r3;
      asm("v_cvt_pk_bf16_f32 %0, %1, %2" : "=v"(r0) : "v"(br[i][0].x), "v"(br[i][0].y));
      asm("v_cvt_pk_bf16_f32 %0, %1, %2" : "=v"(r1) : "v"(br[i][0].z), "v"(br[i][0].w));
      asm("v_cvt_pk_bf16_f32 %0, %1, %2" : "=v"(r2) : "v"(br[i][1].x), "v"(br[i][1].y));
      asm("v_cvt_pk_bf16_f32 %0, %1, %2" : "=v"(r3) : "v"(br[i][1].z), "v"(br[i][1].w));
      u32x4 pk = {r0, r1, r2, r3};
      *reinterpret_cast<u32x4*>((char*)&Bs[0][0] + buf * 16384 + bdst[i]) = pk;
    }
  };

  f32x4 acc[4][4] = {};

  // prologue: fill buffer 0
  astage(0, 0);
  bload(0);
  bwrite(0);
  __syncthreads();

  for (int s = 0; s < 8; ++s) {
    const int cur = s & 1, nxt = cur ^ 1;
    if (s < 7) {
      astage(nxt, s + 1);  // async A -> LDS, in flight across compute
      bload(s + 1);        // B -> regs, in flight across compute
    }
    const char* ab = (const char*)&As[0][0] + cur * 16384;
    const char* bb = (const char*)&Bs[0][0] + cur * 16384;
#pragma unroll
    for (int kk = 0; kk < 64; kk += 32) {
      short8_t a[4], b[4];
#pragma unroll
      for (int fr = 0; fr < 4; ++fr) {
        const int row = wm * 64 + fr * 16 + lrow;
        a[fr] = *reinterpret_cast<const short8_t*>(
            ab + row * 128 + (((kk + lk8) << 1) ^ ((row & 7) << 4)));
      }
#pragma unroll
      for (int fb = 0; fb < 4; ++fb) {
        const int row = wn * 64 + fb * 16 + lrow;
        b[fb] = *reinterpret_cast<const short8_t*>(
            bb + row * 128 + (((kk + lk8) << 1) ^ ((row & 7) << 4)));
      }
#pragma unroll
      for (int fr = 0; fr < 4; ++fr)
#pragma unroll
        for (int fb = 0; fb < 4; ++fb)
          acc[fr][fb] = __builtin_amdgcn_mfma_f32_16x16x32_bf16(a[fr], b[fb], acc[fr][fb], 0, 0, 0);
    }
    if (s < 7) bwrite(nxt);  // vmcnt wait on br, convert, stage into other buffer
    __syncthreads();
  }

  // epilogue: C/D map col=lane&15, row=(lane>>4)*4+reg; store exp(s)
#pragma unroll
  for (int fr = 0; fr < 4; ++fr) {
#pragma unroll
    for (int j = 0; j < 4; ++j) {
      const int grow = my + wm * 64 + fr * 16 + (lane >> 4) * 4 + j;
      float psum = 0.0f;
#pragma unroll
      for (int fb = 0; fb < 4; ++fb) {
        const int col = e0 + wn * 64 + fb * 16 + lrow;
        if (col < N_ENT) {
          float p = __expf(acc[fr][fb][j]);  // |s| small: no max-subtraction
          out[(size_t)grow * N_ENT + col] = p;
          psum += p;
        }
      }
      psum += __shfl_xor(psum, 1);
      psum += __shfl_xor(psum, 2);
      psum += __shfl_xor(psum, 4);
      psum += __shfl_xor(psum, 8);
      if (lrow == 0) atomicAdd(&rowsum[grow], psum);
    }
  }
}

// ---- scaling: factor[i] = scaling_i / rowsum_i (out holds exp(s)) ----
__global__ void scaling_kernel(const float* __restrict__ pun, const float* __restrict__ rowsum,
                               const int* __restrict__ obs_idx, const void* __restrict__ mask,
                               const int* __restrict__ flags, float* __restrict__ factor) {
  int i = threadIdx.x;
  int mode = mask_mode(flags);
  float rs = rowsum[i];
  float sume = 0.0f;
  int cnt = 0;
  for (int j = 0; j < 32; ++j) {
    if (mask_at(mask, i * 32 + j, mode)) {
      int tg = obs_idx[i * 32 + j];
      sume += pun[(size_t)i * N_ENT + tg];
      ++cnt;
    }
  }
  float scaling = 1.0f;
  if (cnt > 0) {
    float denom = fmaxf(sume / rs, 1e-30f);
    scaling = (float)cnt / denom;
  }
  factor[i] = scaling / rs;
}

// ---- finalize: out = clamp(threshold(p_un * factor)) in place ----
__global__ __launch_bounds__(256) void finalize_kernel(float* __restrict__ out,
                                                       const float* __restrict__ factor,
                                                       const int* __restrict__ train) {
  int row = blockIdx.y;
  int i4 = blockIdx.x * blockDim.x + threadIdx.x;
  if (i4 >= N_ENT / 4) return;
  float f = factor[row];
  float hi = (*train) ? (1.0f - 0.001f) : 1.0f;
  float4* p = reinterpret_cast<float4*>(out + (size_t)row * N_ENT) + i4;
  float4 v = *p;
  float vals[4] = {v.x, v.y, v.z, v.w};
#pragma unroll
  for (int j = 0; j < 4; ++j) {
    float s = vals[j] * f;
    s = (s > 1e-4f) ? s : 0.0f;
    vals[j] = fminf(s, hi);
  }
  v.x = vals[0]; v.y = vals[1]; v.z = vals[2]; v.w = vals[3];
  *p = v;
}

// ---- observed positions -> 1.0 (train only) ----
__global__ void scatter_obs_kernel(float* __restrict__ out, const int* __restrict__ obs_idx,
                                   const void* __restrict__ mask, const int* __restrict__ flags,
                                   const int* __restrict__ train) {
  if (!(*train)) return;
  int t = blockIdx.x * blockDim.x + threadIdx.x;
  if (t >= HROWS * MAXOBS) return;
  int mode = mask_mode(flags);
  if (mask_at(mask, t, mode))
    out[(size_t)(t >> 5) * N_ENT + obs_idx[t]] = 1.0f;
}

extern "C" void kernel_launch(void* const* d_in, const int* in_sizes, int n_in,
                              void* d_out, int out_size, void* d_ws, size_t ws_size,
                              hipStream_t stream) {
  const float* ent      = (const float*)d_in[0];
  const float* rel      = (const float*)d_in[1];
  const float* head_vec = (const float*)d_in[2];
  const int* obs_idx    = (const int*)d_in[3];
  const void* obs_mask  = d_in[4];
  const int* rel_id     = (const int*)d_in[5];
  const int* train      = (const int*)d_in[7];
  float* out = (float*)d_out;

  char* ws = (char*)d_ws;
  int*   counter = (int*)(ws + 0);
  int*   flags   = (int*)(ws + 4);
  float* rowsum  = (float*)(ws + 64);
  float* factor  = (float*)(ws + 1088);
  int*   tmp     = (int*)(ws + 2112);
  int*   heads   = (int*)(ws + 3136);
  unsigned short* q = (unsigned short*)(ws + 4224);  // 256x512 bf16

  hipMemsetAsync(ws, 0, 2112, stream);

  detect_mask_kernel<<<1, 256, 0, stream>>>((const unsigned char*)obs_mask, flags);
  find_heads_kernel<<<(N_ENT + 255) / 256, 256, 0, stream>>>(head_vec, counter, tmp);
  sort_heads_kernel<<<1, 256, 0, stream>>>(counter, tmp, heads);
  build_q_kernel<<<HROWS, 256, 0, stream>>>(ent, rel, heads, rel_id, q);
  gemm_scores_kernel<<<dim3((N_ENT + 127) / 128, 2), 256, 0, stream>>>(ent, q, out, rowsum);
  scaling_kernel<<<1, 256, 0, stream>>>(out, rowsum, obs_idx, obs_mask, flags, factor);
  finalize_kernel<<<dim3((N_ENT / 4 + 255) / 256, HROWS), 256, 0, stream>>>(out, factor, train);
  scatter_obs_kernel<<<(HROWS * MAXOBS + 255) / 256, 256, 0, stream>>>(out, obs_idx, obs_mask, flags, train);
}